// Round 1
// baseline (471.139 us; speedup 1.0000x reference)
//
#include <hip/hip_runtime.h>

// Problem constants (setup_inputs): B=8, H=256, W=256, C=64, frame=8
// x:   [8,256,256,64]  f32
// reg: [8,256,256,4]   f32  (reg_in = [...,0:2], reg_out = [...,2:4])
// out: [8,256,256,128] f32
// ws:  xs [256,256,128] f32 = 33.5 MB

// ---------------------------------------------------------------------------
// Kernel 1: fused bilinear-sample(x, reg_in) + max/mean reduction over frame.
// One wave (64 lanes) per output pixel (h,w); lane = channel.
// 4 waves / 256-thread block -> 4 pixels per block, 16384 blocks.
// ---------------------------------------------------------------------------
__global__ __launch_bounds__(256) void share_reduce_kernel(
    const float* __restrict__ x, const float* __restrict__ reg,
    float* __restrict__ xs)
{
    const int wid  = threadIdx.x >> 6;
    const int lane = threadIdx.x & 63;
    const int pix  = (blockIdx.x << 2) + wid;   // 0..65535
    const int h = pix >> 8;
    const int w = pix & 255;

    float vmax = -INFINITY;
    float vsum = 0.f;

#pragma unroll
    for (int b = 0; b < 8; ++b) {
        const float* rp = reg + ((((b << 8) + h) << 8) + w) * 4;
        const float dy = rp[0];
        const float dx = rp[1];
        float cy = fminf(fmaxf((float)h + dy, 0.f), 255.f);
        float cx = fminf(fmaxf((float)w + dx, 0.f), 255.f);
        const float fy0 = floorf(cy);
        const float fx0 = floorf(cx);
        const int y0 = (int)fy0;
        const int x0 = (int)fx0;
        const int y1 = min(y0 + 1, 255);
        const int x1 = min(x0 + 1, 255);
        const float wy = cy - fy0;
        const float wx = cx - fx0;

        const float* xb = x + ((size_t)b << 22);   // b * 256*256*64
        const float v00 = xb[(((y0 << 8) + x0) << 6) + lane];
        const float v01 = xb[(((y0 << 8) + x1) << 6) + lane];
        const float v10 = xb[(((y1 << 8) + x0) << 6) + lane];
        const float v11 = xb[(((y1 << 8) + x1) << 6) + lane];

        const float top = v00 * (1.f - wx) + v01 * wx;
        const float bot = v10 * (1.f - wx) + v11 * wx;
        const float val = top * (1.f - wy) + bot * wy;

        vmax = fmaxf(vmax, val);
        vsum += val;
    }

    float* op = xs + ((size_t)pix << 7);   // pix * 128
    op[lane]      = vmax;            // channels 0..63  : max
    op[64 + lane] = vsum * 0.125f;   // channels 64..127: mean
}

// ---------------------------------------------------------------------------
// Kernel 2: out = share ? bilinear-sample(xs broadcast over b, reg_out)
//                        : concat(x, x).
// One wave per (b,h,w) pixel; 128 channels -> float2 per lane.
// 4 waves / block -> 131072 blocks.
// ---------------------------------------------------------------------------
__global__ __launch_bounds__(256) void share_sample_kernel(
    const float* __restrict__ x, const float* __restrict__ reg,
    const float* __restrict__ xs, const int* __restrict__ share_p,
    float* __restrict__ out)
{
    const int wid  = threadIdx.x >> 6;
    const int lane = threadIdx.x & 63;
    const int pix  = (blockIdx.x << 2) + wid;   // 0..524287
    const int hw = pix & 65535;
    const int h = hw >> 8;
    const int w = hw & 255;

    float* op = out + ((size_t)pix << 7);       // pix * 128

    if (*share_p != 0) {
        const float* rp = reg + (size_t)pix * 4;
        const float dy = rp[2];
        const float dx = rp[3];
        float cy = fminf(fmaxf((float)h + dy, 0.f), 255.f);
        float cx = fminf(fmaxf((float)w + dx, 0.f), 255.f);
        const float fy0 = floorf(cy);
        const float fx0 = floorf(cx);
        const int y0 = (int)fy0;
        const int x0 = (int)fx0;
        const int y1 = min(y0 + 1, 255);
        const int x1 = min(x0 + 1, 255);
        const float wy = cy - fy0;
        const float wx = cx - fx0;

        const float2* r00 = (const float2*)(xs + ((size_t)(((y0 << 8) + x0)) << 7)) + lane;
        const float2* r01 = (const float2*)(xs + ((size_t)(((y0 << 8) + x1)) << 7)) + lane;
        const float2* r10 = (const float2*)(xs + ((size_t)(((y1 << 8) + x0)) << 7)) + lane;
        const float2* r11 = (const float2*)(xs + ((size_t)(((y1 << 8) + x1)) << 7)) + lane;
        const float2 v00 = *r00;
        const float2 v01 = *r01;
        const float2 v10 = *r10;
        const float2 v11 = *r11;

        float2 res;
        {
            const float top = v00.x * (1.f - wx) + v01.x * wx;
            const float bot = v10.x * (1.f - wx) + v11.x * wx;
            res.x = top * (1.f - wy) + bot * wy;
        }
        {
            const float top = v00.y * (1.f - wx) + v01.y * wx;
            const float bot = v10.y * (1.f - wx) + v11.y * wx;
            res.y = top * (1.f - wy) + bot * wy;
        }
        ((float2*)op)[lane] = res;
    } else {
        const float v = x[((size_t)pix << 6) + lane];
        op[lane]      = v;
        op[64 + lane] = v;
    }
}

extern "C" void kernel_launch(void* const* d_in, const int* in_sizes, int n_in,
                              void* d_out, int out_size, void* d_ws, size_t ws_size,
                              hipStream_t stream) {
    const float* x     = (const float*)d_in[0];
    const float* reg   = (const float*)d_in[1];
    const int*   share = (const int*)d_in[3];
    float* out = (float*)d_out;
    float* xs  = (float*)d_ws;   // 256*256*128 f32 = 33.5 MB

    // Kernel 1: 65536 pixels / 4 per block
    share_reduce_kernel<<<65536 / 4, 256, 0, stream>>>(x, reg, xs);
    // Kernel 2: 524288 pixels / 4 per block
    share_sample_kernel<<<524288 / 4, 256, 0, stream>>>(x, reg, xs, share, out);
}

// Round 4
// 428.226 us; speedup vs baseline: 1.1002x; 1.1002x over previous
//
#include <hip/hip_runtime.h>

// Problem constants (setup_inputs): B=8, H=256, W=256, C=64, frame=8
// x:   [8,256,256,64]  f32   (134 MB)
// reg: [8,256,256,4]   f32   (8 MB; reg_in = [...,0:2], reg_out = [...,2:4])
// out: [8,256,256,128] f32   (268 MB)
// ws:  xs [256,256,128] f32  (33.5 MB)

typedef float f32x2 __attribute__((ext_vector_type(2)));
typedef float f32x4 __attribute__((ext_vector_type(4)));

// ---------------------------------------------------------------------------
// Kernel 1: fused bilinear-sample(x, reg_in) + max/mean reduction over frame.
// 2 pixels per wave: half = (tid>>5)&1 selects pixel, ln = tid&31 selects a
// channel PAIR (f32x2). 8 pixels per 256-thread block -> 8192 blocks.
// XCD-chunked swizzle: 8192 blocks -> cpx = 1024.
// ---------------------------------------------------------------------------
__global__ __launch_bounds__(256) void share_reduce_kernel(
    const float* __restrict__ x, const float* __restrict__ reg,
    float* __restrict__ xs)
{
    const int bid  = ((blockIdx.x & 7) << 10) + (blockIdx.x >> 3);
    const int tid  = threadIdx.x;
    const int half = (tid >> 5) & 1;
    const int ln   = tid & 31;
    const int pix  = (bid << 3) + ((tid >> 6) << 1) + half;   // 0..65535
    const int h = pix >> 8;
    const int w = pix & 255;
    const int c = ln << 1;

    float m0 = -INFINITY, m1 = -INFINITY;
    float s0 = 0.f, s1 = 0.f;

#pragma unroll
    for (int b = 0; b < 8; ++b) {
        const f32x2 r = *(const f32x2*)(reg + (size_t)((((b << 8) + h) << 8) + w) * 4);
        float cy = fminf(fmaxf((float)h + r.x, 0.f), 255.f);
        float cx = fminf(fmaxf((float)w + r.y, 0.f), 255.f);
        const float fy0 = floorf(cy);
        const float fx0 = floorf(cx);
        const int y0 = (int)fy0;
        const int x0 = (int)fx0;
        const int y1 = min(y0 + 1, 255);
        const int x1 = min(x0 + 1, 255);
        const float wy = cy - fy0;
        const float wx = cx - fx0;

        const float* xb = x + ((size_t)b << 22);   // b * 256*256*64
        const f32x2 v00 = *(const f32x2*)(xb + ((((y0 << 8) + x0) << 6) + c));
        const f32x2 v01 = *(const f32x2*)(xb + ((((y0 << 8) + x1) << 6) + c));
        const f32x2 v10 = *(const f32x2*)(xb + ((((y1 << 8) + x0) << 6) + c));
        const f32x2 v11 = *(const f32x2*)(xb + ((((y1 << 8) + x1) << 6) + c));

        const float t0 = v00.x * (1.f - wx) + v01.x * wx;
        const float t1 = v00.y * (1.f - wx) + v01.y * wx;
        const float u0 = v10.x * (1.f - wx) + v11.x * wx;
        const float u1 = v10.y * (1.f - wx) + v11.y * wx;
        const float val0 = t0 * (1.f - wy) + u0 * wy;
        const float val1 = t1 * (1.f - wy) + u1 * wy;

        m0 = fmaxf(m0, val0);
        m1 = fmaxf(m1, val1);
        s0 += val0;
        s1 += val1;
    }

    float* op = xs + ((size_t)pix << 7);   // pix * 128
    f32x2 vmax; vmax.x = m0; vmax.y = m1;
    f32x2 vmean; vmean.x = s0 * 0.125f; vmean.y = s1 * 0.125f;
    *(f32x2*)(op + c)      = vmax;    // max  -> ch 0..63
    *(f32x2*)(op + 64 + c) = vmean;   // mean -> ch 64..127
}

// ---------------------------------------------------------------------------
// Kernel 2: out = share ? bilinear-sample(xs broadcast over b, reg_out)
//                        : concat(x, x).
// 2 pixels per wave: half selects pixel, ln = tid&31 selects a channel QUAD
// (f32x4, 128 channels / 32 lanes). 8 pixels/block -> 65536 blocks.
// XCD-chunked swizzle: cpx = 8192. Nontemporal stores for out (write-once).
// ---------------------------------------------------------------------------
__global__ __launch_bounds__(256) void share_sample_kernel(
    const float* __restrict__ x, const float* __restrict__ reg,
    const float* __restrict__ xs, const int* __restrict__ share_p,
    float* __restrict__ out)
{
    const int bid  = ((blockIdx.x & 7) << 13) + (blockIdx.x >> 3);
    const int tid  = threadIdx.x;
    const int half = (tid >> 5) & 1;
    const int ln   = tid & 31;
    const int pix  = (bid << 3) + ((tid >> 6) << 1) + half;   // 0..524287
    const int hw = pix & 65535;
    const int h = hw >> 8;
    const int w = hw & 255;
    const int c = ln << 2;

    float* op = out + ((size_t)pix << 7);   // pix * 128

    if (*share_p != 0) {
        const f32x4 r = *(const f32x4*)(reg + (size_t)pix * 4);
        float cy = fminf(fmaxf((float)h + r.z, 0.f), 255.f);
        float cx = fminf(fmaxf((float)w + r.w, 0.f), 255.f);
        const float fy0 = floorf(cy);
        const float fx0 = floorf(cx);
        const int y0 = (int)fy0;
        const int x0 = (int)fx0;
        const int y1 = min(y0 + 1, 255);
        const int x1 = min(x0 + 1, 255);
        const float wy = cy - fy0;
        const float wx = cx - fx0;

        const f32x4 v00 = *(const f32x4*)(xs + (((size_t)((y0 << 8) + x0)) << 7) + c);
        const f32x4 v01 = *(const f32x4*)(xs + (((size_t)((y0 << 8) + x1)) << 7) + c);
        const f32x4 v10 = *(const f32x4*)(xs + (((size_t)((y1 << 8) + x0)) << 7) + c);
        const f32x4 v11 = *(const f32x4*)(xs + (((size_t)((y1 << 8) + x1)) << 7) + c);

        const f32x4 top = v00 * (1.f - wx) + v01 * wx;
        const f32x4 bot = v10 * (1.f - wx) + v11 * wx;
        const f32x4 res = top * (1.f - wy) + bot * wy;
        __builtin_nontemporal_store(res, (f32x4*)(op + c));
    } else {
        const f32x4 v = *(const f32x4*)(x + ((size_t)pix << 6) + (c & 63));
        __builtin_nontemporal_store(v, (f32x4*)(op + c));
    }
}

extern "C" void kernel_launch(void* const* d_in, const int* in_sizes, int n_in,
                              void* d_out, int out_size, void* d_ws, size_t ws_size,
                              hipStream_t stream) {
    const float* x     = (const float*)d_in[0];
    const float* reg   = (const float*)d_in[1];
    const int*   share = (const int*)d_in[3];
    float* out = (float*)d_out;
    float* xs  = (float*)d_ws;   // 256*256*128 f32 = 33.5 MB

    // Kernel 1: 65536 pixels, 8 per block
    share_reduce_kernel<<<8192, 256, 0, stream>>>(x, reg, xs);
    // Kernel 2: 524288 pixels, 8 per block
    share_sample_kernel<<<65536, 256, 0, stream>>>(x, reg, xs, share, out);
}